// Round 8
// baseline (113.268 us; speedup 1.0000x reference)
//
#include <hip/hip_runtime.h>
#include <hip/hip_bf16.h>
#include <math.h>

// Contrastive (NT-Xent-like) loss over x[16384][64] fp32.
//   x_hat = sqrt(2*log2e) * x / ||x||   (so x_hat_i.x_hat_j = sim/T * log2e,
//                                        and exp(sim/T) = exp2(x_hat_i.x_hat_j))
//   den[j] = sum_i exp2(x_hat_i . x_hat_j) - e^2
//   num[j] = exp2(x_hat_{j^1} . x_hat_j)
//   out = -log( mean_j num[j] / den[j] )
//
// Round 8: r7's single-kernel ticket/spin hung (or faulted) the harness —
// abandoned. Lesson pair r5+r7: per-block agent fences = buffer_wbl2 storm
// (fatal); end-of-grid spins = unverifiable; the KERNEL BOUNDARY is the one
// cheap, correct cross-XCD flush. This round = r6's proven 3-kernel skeleton
// minus two dispatches, keeping only the safe r7 pieces:
//   (1) normalization fused into den staging (8 lanes/row butterfly ||row||^2,
//       scale, cvt bf16, same swizzled ds_write) — normalize kernel + xnb gone;
//   (2) ctrl/accum zeroed by den block 0 with plain stores (boundary
//       publishes them) — memset dispatch gone.
// Kept (r3-r6 counter-verified): XOR-swizzled conflict-free LDS, 2x2 wave
// MFMA 16x16x32_bf16, exp2 prescale, value-halving butterflies, exactly-once
// plain S/num stores, f32 triangular decode, 32 KB LDS (5 blocks/CU).

#define NROWS 16384
#define KDIM 64
#define NTILE 128
#define NTB (NROWS / NTILE)          // 128 tile-blocks per side
#define NPAIRS (NTB * (NTB + 1) / 2) // 8256 upper-triangle tile pairs

typedef __attribute__((ext_vector_type(8))) short short8;   // 8 bf16 = 4 VGPRs
typedef __attribute__((ext_vector_type(4))) float f32x4;

__device__ __forceinline__ float exp2_fast(float x) {
#if __has_builtin(__builtin_amdgcn_exp2f)
    return __builtin_amdgcn_exp2f(x);   // bare v_exp_f32
#else
    return exp2f(x);
#endif
}

__device__ __forceinline__ float sumsq8(const float4 a, const float4 b) {
    return a.x * a.x + a.y * a.y + a.z * a.z + a.w * a.w
         + b.x * b.x + b.y * b.y + b.z * b.z + b.w * b.w;
}

__device__ __forceinline__ float4 pack8_bf16(const float4 v0, const float4 v1, const float k) {
    union { unsigned short us[8]; float4 f4; } o;
    const float v[8] = {v0.x * k, v0.y * k, v0.z * k, v0.w * k,
                        v1.x * k, v1.y * k, v1.z * k, v1.w * k};
    #pragma unroll
    for (int i = 0; i < 8; i++) {
        __hip_bfloat16 b = __float2bfloat16(v[i]);
        o.us[i] = *(unsigned short*)&b;
    }
    return o.f4;
}

// ---- kernel A: symmetric tile-pair partial sums (normalization fused) -----
// Block = upper-triangle tile pair (ti<=tj). 4 waves 2x2, 64x64/wave,
// mfma_f32_16x16x32_bf16 (A-frag: lane m=l&15 holds k=(l>>4)*8+e;
// C/D: col=l&15, row=(l>>4)*4+reg). LDS chunk(r,q) at r*8 + (q^(r&7)):
// coalesced staging, ~0 bank conflicts (verified r3-r6). LDS exactly 32 KB.
__global__ __launch_bounds__(256) void den_kernel(const float* __restrict__ x,
                                                  float* __restrict__ S,
                                                  float* __restrict__ num,
                                                  unsigned int* __restrict__ ctrl,
                                                  float* __restrict__ accum) {
    __shared__ float4 As[1024];  // 16 KB; aliased as reduction scratch later
    __shared__ float4 Bs[1024];  // 16 KB

    // triangular decode (f32; loops absorb rounding): blockIdx.x -> (ti, tj)
    const int bt = blockIdx.x;
    int ti = (int)((257.0f - sqrtf(66049.0f - 8.0f * (float)bt)) * 0.5f);
    while (ti * NTB - ti * (ti - 1) / 2 > bt) ti--;
    while ((ti + 1) * NTB - (ti + 1) * ti / 2 <= bt) ti++;
    const int tj = ti + (bt - (ti * NTB - ti * (ti - 1) / 2));
    const int ib = ti * NTILE, jb = tj * NTILE;
    const bool diag = (ti == tj);

    const int t = threadIdx.x;
    if (bt == 0 && t == 0) { ctrl[0] = 0u; ctrl[1] = 0u; accum[0] = 0.0f; }  // published by kernel boundary

    // staging + fused normalization: chunk c -> row r=c>>3, k-chunk q=(c&7)^(r&7).
    // The 8 lanes sharing a row are t&~7..t|7 (same wave): butterfly ||row||^2
    // (each lane holds a distinct 8-elem chunk of the row -> 3 shuffles).
    #pragma unroll
    for (int s = 0; s < 4; s++) {
        const int c = s * 256 + t;
        const int r = c >> 3;
        const int q = (c & 7) ^ (r & 7);
        const float4 a0 = *(const float4*)&x[(size_t)(ib + r) * KDIM + q * 8];
        const float4 a1 = *(const float4*)&x[(size_t)(ib + r) * KDIM + q * 8 + 4];
        const float4 b0 = *(const float4*)&x[(size_t)(jb + r) * KDIM + q * 8];
        const float4 b1 = *(const float4*)&x[(size_t)(jb + r) * KDIM + q * 8 + 4];
        float ssa = sumsq8(a0, a1), ssb = sumsq8(b0, b1);
        ssa += __shfl_xor(ssa, 1, 64);  ssb += __shfl_xor(ssb, 1, 64);
        ssa += __shfl_xor(ssa, 2, 64);  ssb += __shfl_xor(ssb, 2, 64);
        ssa += __shfl_xor(ssa, 4, 64);  ssb += __shfl_xor(ssb, 4, 64);
        // sqrt(2*log2(e)) = 1.69864404
        const float ka = 1.69864404f * rsqrtf(fmaxf(ssa, 1e-16f));
        const float kb = 1.69864404f * rsqrtf(fmaxf(ssb, 1e-16f));
        As[c] = pack8_bf16(a0, a1, ka);
        Bs[c] = pack8_bf16(b0, b1, kb);
    }
    __syncthreads();

    const int lane = t & 63, w = t >> 6;
    const int wi = w >> 1, wj = w & 1;
    const int m = lane & 15, p = lane >> 4;

    const f32x4 zero = {0.f, 0.f, 0.f, 0.f};
    f32x4 acc[4][4];
    #pragma unroll
    for (int it = 0; it < 4; it++)
        #pragma unroll
        for (int jt = 0; jt < 4; jt++) acc[it][jt] = zero;

    #pragma unroll
    for (int kc = 0; kc < 2; kc++) {
        short8 af[4], bf[4];
        const int qx = ((kc << 2) | p) ^ (m & 7);
        #pragma unroll
        for (int it = 0; it < 4; it++) {
            af[it] = *(const short8*)((const unsigned short*)As + ((wi * 64 + it * 16 + m) * 8 + qx) * 8);
            bf[it] = *(const short8*)((const unsigned short*)Bs + ((wj * 64 + it * 16 + m) * 8 + qx) * 8);
        }
        #pragma unroll
        for (int it = 0; it < 4; it++)
            #pragma unroll
            for (int jt = 0; jt < 4; jt++)
                acc[it][jt] = __builtin_amdgcn_mfma_f32_16x16x32_bf16(af[it], bf[jt], acc[it][jt], 0, 0, 0);
    }

    // epilogue: exp2 (bare v_exp); col partials cs[jt], row partials rs[it*4+reg]
    float cs[4] = {0.f, 0.f, 0.f, 0.f};
    float rs[16];
    #pragma unroll
    for (int it = 0; it < 4; it++) {
        #pragma unroll
        for (int reg = 0; reg < 4; reg++) {
            const float e0 = exp2_fast(acc[it][0][reg]);
            const float e1 = exp2_fast(acc[it][1][reg]);
            const float e2 = exp2_fast(acc[it][2][reg]);
            const float e3 = exp2_fast(acc[it][3][reg]);
            cs[0] += e0; cs[1] += e1; cs[2] += e2; cs[3] += e3;
            rs[it * 4 + reg] = (e0 + e1) + (e2 + e3);
        }
    }

    // colsum butterfly over p (value-halving): lane ends with column p*16+m
    {
        const bool hb = (p & 2) != 0;
        float s0 = hb ? cs[0] : cs[2], k0 = hb ? cs[2] : cs[0];
        float s1 = hb ? cs[1] : cs[3], k1 = hb ? cs[3] : cs[1];
        cs[0] = k0 + __shfl_xor(s0, 32, 64);
        cs[1] = k1 + __shfl_xor(s1, 32, 64);
        const bool lb = (p & 1) != 0;
        float s2 = lb ? cs[0] : cs[1], k2 = lb ? cs[1] : cs[0];
        cs[0] = k2 + __shfl_xor(s2, 16, 64);
    }

    // rowsum butterfly over m (value-halving, 15 shfl): lane ends with row
    // (m>>2)*16 + p*4 + (m&3)
    if (!diag) {
        #pragma unroll
        for (int k = 0; k < 8; k++) {
            const float snd = (m & 8) ? rs[k] : rs[k + 8];
            const float kp  = (m & 8) ? rs[k + 8] : rs[k];
            rs[k] = kp + __shfl_xor(snd, 8, 64);
        }
        #pragma unroll
        for (int k = 0; k < 4; k++) {
            const float snd = (m & 4) ? rs[k] : rs[k + 4];
            const float kp  = (m & 4) ? rs[k + 4] : rs[k];
            rs[k] = kp + __shfl_xor(snd, 4, 64);
        }
        #pragma unroll
        for (int k = 0; k < 2; k++) {
            const float snd = (m & 2) ? rs[k] : rs[k + 2];
            const float kp  = (m & 2) ? rs[k + 2] : rs[k];
            rs[k] = kp + __shfl_xor(snd, 2, 64);
        }
        {
            const float snd = (m & 1) ? rs[0] : rs[1];
            const float kp  = (m & 1) ? rs[1] : rs[0];
            rs[0] = kp + __shfl_xor(snd, 1, 64);
        }
    } else if (wi == wj) {
        // num[j] = exp2(acc(row j^1, col j)) from the diagonal tile: element
        // (m^1, m) of sub-tile it lives in lane ((m^1)>>2, m), reg (m^1)&3.
        const int pc = m ^ 1;
        if ((pc >> 2) == p) {
            #pragma unroll
            for (int it = 0; it < 4; it++)
                num[jb + wj * 64 + it * 16 + m] = exp2_fast(acc[it][it][pc & 3]);
        }
    }

    // cross-wave combine through LDS (aliases dead As)
    float* red = (float*)As;   // [0..255] colsums by wi; [256..511] rowsums by wj
    __syncthreads();           // all waves done reading As/Bs
    red[wi * 128 + wj * 64 + p * 16 + m] = cs[0];
    if (!diag) red[256 + wj * 128 + wi * 64 + ((m >> 2) * 16 + p * 4 + (m & 3))] = rs[0];
    __syncthreads();

    // exactly-once coalesced partial stores (no atomics, no fences):
    //   colsums -> S[tj][ti][c] (den[jb+c]); rowsums -> S[ti][tj][r] (den[ib+r])
    if (t < NTILE) {
        S[((size_t)tj * NTB + ti) * NTILE + t] = red[t] + red[128 + t];
    } else if (!diag) {
        const int u = t - NTILE;
        S[((size_t)ti * NTB + tj) * NTILE + u] = red[256 + u] + red[256 + 128 + u];
    }
}

// ---- kernel B: den[a*128+c] = sum_b S[a][b][c]; ratio + global sum + log ---
// 128 blocks; ticket write of the final scalar (r6-verified).
__global__ __launch_bounds__(256) void reduce_kernel(const float* __restrict__ S,
                                                     const float* __restrict__ num,
                                                     unsigned int* __restrict__ ctrl,
                                                     float* __restrict__ accum,
                                                     float* __restrict__ out) {
    const int a = blockIdx.x;
    const int t = threadIdx.x;
    const int c = t & 127, h = t >> 7;     // h splits the b-range in two
    const float* base = S + (size_t)a * (NTB * NTILE) + (size_t)h * 64 * NTILE + c;
    float s = 0.0f;
    #pragma unroll 8
    for (int b = 0; b < 64; b++) s += base[(size_t)b * NTILE];

    __shared__ float part[NTILE];
    __shared__ float wsum[4];
    if (h == 0) part[c] = s;
    __syncthreads();

    float r = 0.0f;
    if (h == 1) {
        const float E2 = 7.38905609893065f;  // exp(1/T)=exp(2): diagonal removal
        r = num[a * NTILE + c] / ((part[c] + s) - E2);
    }
    #pragma unroll
    for (int o = 32; o > 0; o >>= 1) r += __shfl_xor(r, o, 64);
    if ((t & 63) == 0) wsum[t >> 6] = r;
    __syncthreads();
    if (t == 0) {
        const float bsum = (wsum[0] + wsum[1]) + (wsum[2] + wsum[3]);
        __hip_atomic_fetch_add(accum, bsum, __ATOMIC_RELAXED, __HIP_MEMORY_SCOPE_AGENT);
        const unsigned int tk = __hip_atomic_fetch_add(&ctrl[1], 1u, __ATOMIC_ACQ_REL, __HIP_MEMORY_SCOPE_AGENT);
        if (tk == (unsigned)(NTB - 1)) {   // last block writes the loss
            const float total = __hip_atomic_load(accum, __ATOMIC_ACQUIRE, __HIP_MEMORY_SCOPE_AGENT);
            out[0] = -logf(total / (float)NROWS);
        }
    }
}

extern "C" void kernel_launch(void* const* d_in, const int* in_sizes, int n_in,
                              void* d_out, int out_size, void* d_ws, size_t ws_size,
                              hipStream_t stream) {
    const float* x = (const float*)d_in[0];
    float* out = (float*)d_out;

    // ws: ctrl [2 u32] + accum [1 f32] + pad to 16 B | S [8 MB f32] | num [64 KB f32]
    unsigned int* ctrl = (unsigned int*)d_ws;
    float* accum = (float*)(ctrl + 2);
    float* S = (float*)((char*)d_ws + 16);
    float* num = S + (size_t)NTB * NTB * NTILE;

    den_kernel<<<NPAIRS, 256, 0, stream>>>(x, S, num, ctrl, accum);
    reduce_kernel<<<NTB, 256, 0, stream>>>(S, num, ctrl, accum, out);
}

// Round 9
// 100.802 us; speedup vs baseline: 1.1237x; 1.1237x over previous
//
#include <hip/hip_runtime.h>
#include <hip/hip_bf16.h>
#include <math.h>

// Contrastive (NT-Xent-like) loss over x[16384][64] fp32.
//   x_hat = sqrt(2*log2e) * x / ||x||   (so x_hat_i.x_hat_j = sim/T * log2e,
//                                        and exp(sim/T) = exp2(x_hat_i.x_hat_j))
//   den[j] = sum_i exp2(x_hat_i . x_hat_j) - e^2
//   num[j] = exp2(x_hat_{j^1} . x_hat_j)
//   out = -log( mean_j num[j] / den[j] )
//
// Round 9: r8 taught (a) fused normalization is 128x-redundant (den 46->61,
// FETCH 2x) -> revert to separate bf16-prebake normalize; (b) the ~50 us
// non-kernel residual is FIXED harness overhead (invariant across 5->2
// dispatches) -> optimize kernel time only. New this round, on the r6-proven
// skeleton: (1) global_load_lds width=16 staging — our swizzled chunk index
// is lane-consecutive (LDS dest = wave-uniform base + lane*16, the required
// pattern; the XOR swizzle is on the per-lane GLOBAL address, which is
// allowed) — kills the ds_write + register round-trip; (2) packed f32x2
// epilogue accumulation (v_pk_add_f32): 7 scalar adds/(it,reg) -> 4 packed.
// Kept verified: XOR-swizzle (0 conflicts), 2x2 wave MFMA 16x16x32_bf16,
// exp2 prescale, value-halving butterflies, exactly-once S stores, kernel
// boundary as the only cross-XCD flush (r5/r7 lessons), 32 KB LDS.

#define NROWS 16384
#define KDIM 64
#define NTILE 128
#define NTB (NROWS / NTILE)          // 128 tile-blocks per side
#define NPAIRS (NTB * (NTB + 1) / 2) // 8256 upper-triangle tile pairs

typedef __attribute__((ext_vector_type(8))) short short8;   // 8 bf16 = 4 VGPRs
typedef __attribute__((ext_vector_type(4))) float f32x4;
typedef __attribute__((ext_vector_type(2))) float f32x2;

__device__ __forceinline__ float exp2_fast(float x) {
#if __has_builtin(__builtin_amdgcn_exp2f)
    return __builtin_amdgcn_exp2f(x);   // bare v_exp_f32
#else
    return exp2f(x);
#endif
}

// async global->LDS DMA, 16 B per lane; LDS side must be uniform + lane*16.
__device__ __forceinline__ void load_lds16(const void* g, void* l) {
    __builtin_amdgcn_global_load_lds((const __attribute__((address_space(1))) unsigned int*)g,
                                     (__attribute__((address_space(3))) unsigned int*)l,
                                     16, 0, 0);
}

// ---- kernel A: row-normalize, prescale by sqrt(2*log2e) -> bf16 -----------
// 64 rows/block, 4 lanes/row, 16 floats/thread. Also zeroes ctrl/accum.
__global__ __launch_bounds__(256) void normalize_kernel(const float* __restrict__ x,
                                                        unsigned short* __restrict__ xnb,
                                                        unsigned int* __restrict__ ctrl,
                                                        float* __restrict__ accum) {
    const int t = threadIdx.x;
    const int r = blockIdx.x * 64 + (t >> 2);
    const int q = t & 3;
    const float4* xr = (const float4*)(x + (size_t)r * KDIM) + q * 4;
    const float4 v0 = xr[0], v1 = xr[1], v2 = xr[2], v3 = xr[3];
    float ss = v0.x * v0.x + v0.y * v0.y + v0.z * v0.z + v0.w * v0.w
             + v1.x * v1.x + v1.y * v1.y + v1.z * v1.z + v1.w * v1.w
             + v2.x * v2.x + v2.y * v2.y + v2.z * v2.z + v2.w * v2.w
             + v3.x * v3.x + v3.y * v3.y + v3.z * v3.z + v3.w * v3.w;
    ss += __shfl_xor(ss, 1, 64);
    ss += __shfl_xor(ss, 2, 64);
    // sqrt(2*log2(e)) = sqrt(2.88539008) = 1.69864404
    const float a = 1.69864404f * rsqrtf(fmaxf(ss, 1e-16f));
    const float vals[16] = {v0.x * a, v0.y * a, v0.z * a, v0.w * a,
                            v1.x * a, v1.y * a, v1.z * a, v1.w * a,
                            v2.x * a, v2.y * a, v2.z * a, v2.w * a,
                            v3.x * a, v3.y * a, v3.z * a, v3.w * a};
    union { unsigned short us[16]; uint4 v[2]; } o;
    #pragma unroll
    for (int k = 0; k < 16; k++) {
        __hip_bfloat16 b = __float2bfloat16(vals[k]);
        o.us[k] = *(unsigned short*)&b;
    }
    uint4* dst = (uint4*)(xnb + (size_t)r * KDIM);
    dst[q * 2] = o.v[0];
    dst[q * 2 + 1] = o.v[1];
    if (blockIdx.x == 0 && t == 0) { ctrl[0] = 0u; ctrl[1] = 0u; accum[0] = 0.0f; }
}

// ---- kernel B: symmetric tile-pair partial sums ---------------------------
// Block = upper-triangle tile pair (ti<=tj). 4 waves 2x2, 64x64/wave,
// mfma_f32_16x16x32_bf16 (A-frag: lane m=l&15 holds k=(l>>4)*8+e;
// C/D: col=l&15, row=(l>>4)*4+reg). LDS chunk(r,q) at r*8 + (q^(r&7)):
// staged via global_load_lds_dwordx4 (lane-consecutive LDS dest). 32 KB LDS.
__global__ __launch_bounds__(256) void den_kernel(const unsigned short* __restrict__ xnb,
                                                  float* __restrict__ S,
                                                  float* __restrict__ num) {
    __shared__ float4 As[1024];  // 16 KB; aliased as reduction scratch later
    __shared__ float4 Bs[1024];  // 16 KB

    // triangular decode (f32; loops absorb rounding): blockIdx.x -> (ti, tj)
    const int bt = blockIdx.x;
    int ti = (int)((257.0f - sqrtf(66049.0f - 8.0f * (float)bt)) * 0.5f);
    while (ti * NTB - ti * (ti - 1) / 2 > bt) ti--;
    while ((ti + 1) * NTB - (ti + 1) * ti / 2 <= bt) ti++;
    const int tj = ti + (bt - (ti * NTB - ti * (ti - 1) / 2));
    const int ib = ti * NTILE, jb = tj * NTILE;
    const bool diag = (ti == tj);

    const int t = threadIdx.x;
    // staging: chunk c -> row r=c>>3, k-chunk q=(c&7)^(r&7). Global side is a
    // per-lane VGPR address (swizzle allowed); LDS side is uniform + lane*16.
    #pragma unroll
    for (int s = 0; s < 4; s++) {
        const int c = s * 256 + t;
        const int r = c >> 3;
        const int q = (c & 7) ^ (r & 7);
        load_lds16(xnb + (size_t)(ib + r) * KDIM + q * 8, &As[c]);
        load_lds16(xnb + (size_t)(jb + r) * KDIM + q * 8, &Bs[c]);
    }
    __syncthreads();   // compiler emits vmcnt(0) drain before s_barrier

    const int lane = t & 63, w = t >> 6;
    const int wi = w >> 1, wj = w & 1;
    const int m = lane & 15, p = lane >> 4;

    const f32x4 zero = {0.f, 0.f, 0.f, 0.f};
    f32x4 acc[4][4];
    #pragma unroll
    for (int it = 0; it < 4; it++)
        #pragma unroll
        for (int jt = 0; jt < 4; jt++) acc[it][jt] = zero;

    #pragma unroll
    for (int kc = 0; kc < 2; kc++) {
        short8 af[4], bf[4];
        const int qx = ((kc << 2) | p) ^ (m & 7);
        #pragma unroll
        for (int it = 0; it < 4; it++) {
            af[it] = *(const short8*)((const unsigned short*)As + ((wi * 64 + it * 16 + m) * 8 + qx) * 8);
            bf[it] = *(const short8*)((const unsigned short*)Bs + ((wj * 64 + it * 16 + m) * 8 + qx) * 8);
        }
        #pragma unroll
        for (int it = 0; it < 4; it++)
            #pragma unroll
            for (int jt = 0; jt < 4; jt++)
                acc[it][jt] = __builtin_amdgcn_mfma_f32_16x16x32_bf16(af[it], bf[jt], acc[it][jt], 0, 0, 0);
    }

    // epilogue: exp2; packed (v_pk_add_f32) accumulation of col/row partials
    f32x2 cs01 = {0.f, 0.f}, cs23 = {0.f, 0.f};
    float rs[16];
    #pragma unroll
    for (int it = 0; it < 4; it++) {
        #pragma unroll
        for (int reg = 0; reg < 4; reg++) {
            f32x2 e01, e23;
            e01.x = exp2_fast(acc[it][0][reg]);
            e01.y = exp2_fast(acc[it][1][reg]);
            e23.x = exp2_fast(acc[it][2][reg]);
            e23.y = exp2_fast(acc[it][3][reg]);
            cs01 += e01;                  // 1 pk_add (cs[0], cs[1])
            cs23 += e23;                  // 1 pk_add (cs[2], cs[3])
            const f32x2 rp = e01 + e23;   // 1 pk_add
            rs[it * 4 + reg] = rp.x + rp.y;
        }
    }
    float cs[4] = {cs01.x, cs01.y, cs23.x, cs23.y};

    // colsum butterfly over p (value-halving): lane ends with column p*16+m
    {
        const bool hb = (p & 2) != 0;
        float s0 = hb ? cs[0] : cs[2], k0 = hb ? cs[2] : cs[0];
        float s1 = hb ? cs[1] : cs[3], k1 = hb ? cs[3] : cs[1];
        cs[0] = k0 + __shfl_xor(s0, 32, 64);
        cs[1] = k1 + __shfl_xor(s1, 32, 64);
        const bool lb = (p & 1) != 0;
        float s2 = lb ? cs[0] : cs[1], k2 = lb ? cs[1] : cs[0];
        cs[0] = k2 + __shfl_xor(s2, 16, 64);
    }

    // rowsum butterfly over m (value-halving, 15 shfl): lane ends with row
    // (m>>2)*16 + p*4 + (m&3)
    if (!diag) {
        #pragma unroll
        for (int k = 0; k < 8; k++) {
            const float snd = (m & 8) ? rs[k] : rs[k + 8];
            const float kp  = (m & 8) ? rs[k + 8] : rs[k];
            rs[k] = kp + __shfl_xor(snd, 8, 64);
        }
        #pragma unroll
        for (int k = 0; k < 4; k++) {
            const float snd = (m & 4) ? rs[k] : rs[k + 4];
            const float kp  = (m & 4) ? rs[k + 4] : rs[k];
            rs[k] = kp + __shfl_xor(snd, 4, 64);
        }
        #pragma unroll
        for (int k = 0; k < 2; k++) {
            const float snd = (m & 2) ? rs[k] : rs[k + 2];
            const float kp  = (m & 2) ? rs[k + 2] : rs[k];
            rs[k] = kp + __shfl_xor(snd, 2, 64);
        }
        {
            const float snd = (m & 1) ? rs[0] : rs[1];
            const float kp  = (m & 1) ? rs[1] : rs[0];
            rs[0] = kp + __shfl_xor(snd, 1, 64);
        }
    } else if (wi == wj) {
        // num[j] = exp2(acc(row j^1, col j)) from the diagonal tile: element
        // (m^1, m) of sub-tile it lives in lane ((m^1)>>2, m), reg (m^1)&3.
        const int pc = m ^ 1;
        if ((pc >> 2) == p) {
            #pragma unroll
            for (int it = 0; it < 4; it++)
                num[jb + wj * 64 + it * 16 + m] = exp2_fast(acc[it][it][pc & 3]);
        }
    }

    // cross-wave combine through LDS (aliases dead As)
    float* red = (float*)As;   // [0..255] colsums by wi; [256..511] rowsums by wj
    __syncthreads();           // all waves done reading As/Bs
    red[wi * 128 + wj * 64 + p * 16 + m] = cs[0];
    if (!diag) red[256 + wj * 128 + wi * 64 + ((m >> 2) * 16 + p * 4 + (m & 3))] = rs[0];
    __syncthreads();

    // exactly-once coalesced partial stores (no atomics, no fences):
    //   colsums -> S[tj][ti][c] (den[jb+c]); rowsums -> S[ti][tj][r] (den[ib+r])
    if (t < NTILE) {
        S[((size_t)tj * NTB + ti) * NTILE + t] = red[t] + red[128 + t];
    } else if (!diag) {
        const int u = t - NTILE;
        S[((size_t)ti * NTB + tj) * NTILE + u] = red[256 + u] + red[256 + 128 + u];
    }
}

// ---- kernel C: den[a*128+c] = sum_b S[a][b][c]; ratio + global sum + log ---
// 128 blocks; ticket write of the final scalar (r6-verified).
__global__ __launch_bounds__(256) void reduce_kernel(const float* __restrict__ S,
                                                     const float* __restrict__ num,
                                                     unsigned int* __restrict__ ctrl,
                                                     float* __restrict__ accum,
                                                     float* __restrict__ out) {
    const int a = blockIdx.x;
    const int t = threadIdx.x;
    const int c = t & 127, h = t >> 7;     // h splits the b-range in two
    const float* base = S + (size_t)a * (NTB * NTILE) + (size_t)h * 64 * NTILE + c;
    float s = 0.0f;
    #pragma unroll 8
    for (int b = 0; b < 64; b++) s += base[(size_t)b * NTILE];

    __shared__ float part[NTILE];
    __shared__ float wsum[4];
    if (h == 0) part[c] = s;
    __syncthreads();

    float r = 0.0f;
    if (h == 1) {
        const float E2 = 7.38905609893065f;  // exp(1/T)=exp(2): diagonal removal
        r = num[a * NTILE + c] / ((part[c] + s) - E2);
    }
    #pragma unroll
    for (int o = 32; o > 0; o >>= 1) r += __shfl_xor(r, o, 64);
    if ((t & 63) == 0) wsum[t >> 6] = r;
    __syncthreads();
    if (t == 0) {
        const float bsum = (wsum[0] + wsum[1]) + (wsum[2] + wsum[3]);
        __hip_atomic_fetch_add(accum, bsum, __ATOMIC_RELAXED, __HIP_MEMORY_SCOPE_AGENT);
        const unsigned int tk = __hip_atomic_fetch_add(&ctrl[1], 1u, __ATOMIC_ACQ_REL, __HIP_MEMORY_SCOPE_AGENT);
        if (tk == (unsigned)(NTB - 1)) {   // last block writes the loss
            const float total = __hip_atomic_load(accum, __ATOMIC_ACQUIRE, __HIP_MEMORY_SCOPE_AGENT);
            out[0] = -logf(total / (float)NROWS);
        }
    }
}

extern "C" void kernel_launch(void* const* d_in, const int* in_sizes, int n_in,
                              void* d_out, int out_size, void* d_ws, size_t ws_size,
                              hipStream_t stream) {
    const float* x = (const float*)d_in[0];
    float* out = (float*)d_out;

    // ws: xnb [2 MB bf16] | num [64 KB f32] | accum [1 f32] | ctrl [2 u32] | S [8 MB f32]
    unsigned short* xnb = (unsigned short*)d_ws;
    float* num = (float*)((char*)d_ws + (size_t)NROWS * KDIM * sizeof(unsigned short));
    float* accum = num + NROWS;
    unsigned int* ctrl = (unsigned int*)(accum + 1);
    float* S = (float*)(ctrl + 2);

    normalize_kernel<<<NROWS / 64, 256, 0, stream>>>(x, xnb, ctrl, accum);
    den_kernel<<<NPAIRS, 256, 0, stream>>>(xnb, S, num);
    reduce_kernel<<<NTB, 256, 0, stream>>>(S, num, ctrl, accum, out);
}